// Round 15
// baseline (1029.126 us; speedup 1.0000x reference)
//
#include <hip/hip_runtime.h>
#include <hip/hip_bf16.h>
#include <math.h>

typedef unsigned int u32;
typedef unsigned short u16;
typedef __bf16 bf16t;
typedef bf16t bf16x8 __attribute__((ext_vector_type(8)));
typedef float f32x4 __attribute__((ext_vector_type(4)));

__device__ __forceinline__ u16 f2bf(float f) {
    u32 u = __builtin_bit_cast(u32, f);
    u32 r = (u + 0x7fffu + ((u >> 16) & 1u)) >> 16;
    return (u16)r;
}
__device__ __forceinline__ float bf2f(u16 x) {
    u32 u = ((u32)x) << 16;
    return __builtin_bit_cast(float, u);
}

__device__ __forceinline__ float gelu_f(float x) {
    float z = fabsf(x) * 0.70710678118654752f;
    float t = 1.f / (1.f + 0.3275911f * z);
    float poly = t * (0.254829592f + t * (-0.284496736f + t * (1.421413741f +
                 t * (-1.453152027f + t * 1.061405429f))));
    float erfz = 1.f - poly * __expf(-z * z);
    erfz = copysignf(erfz, x);
    return 0.5f * x * (1.f + erfz);
}

__device__ __forceinline__ void gl_lds16(const u16* g, u16* l) {
    __builtin_amdgcn_global_load_lds(
        (const __attribute__((address_space(1))) void*)g,
        (__attribute__((address_space(3))) void*)l, 16, 0, 0);
}

__device__ __forceinline__ void wait_vm0_barrier() {
    asm volatile("s_waitcnt vmcnt(0)" ::: "memory");
    __builtin_amdgcn_s_barrier();
}

template<int N> __device__ __forceinline__ void s_wait_vmcnt() {
    if constexpr (N == 0) asm volatile("s_waitcnt vmcnt(0)" ::: "memory");
    else if constexpr (N == 2) asm volatile("s_waitcnt vmcnt(2)" ::: "memory");
    else if constexpr (N == 3) asm volatile("s_waitcnt vmcnt(3)" ::: "memory");
    else if constexpr (N == 4) asm volatile("s_waitcnt vmcnt(4)" ::: "memory");
    else if constexpr (N == 6) asm volatile("s_waitcnt vmcnt(6)" ::: "memory");
    else if constexpr (N == 8) asm volatile("s_waitcnt vmcnt(8)" ::: "memory");
    else static_assert(N == 0, "unsupported vmcnt");
}

// ---------------- weight layout transforms (-> bf16, (o, k*512+i)) ----------------
__global__ void tdeconv_k(const float* __restrict__ src, u16* __restrict__ dst) {
    int o = blockIdx.x;
    for (int i = threadIdx.x; i < 512; i += blockDim.x) {
        const float* s = src + ((size_t)i * 512 + o) * 5;   // deconv_w (in, out, K)
        #pragma unroll
        for (int k = 0; k < 5; ++k)
            dst[(size_t)o * 2560 + k * 512 + i] = f2bf(s[k]);
    }
}
__global__ void tconv_k(const float* __restrict__ src, u16* __restrict__ dst) {
    int o = blockIdx.x, st = blockIdx.y;
    const float* bsrc = src + (size_t)st * 512 * 512 * 5;   // conv_w (2, out, in, K)
    u16* bdst = dst + (size_t)st * 512 * 2560;
    for (int i = threadIdx.x; i < 512; i += blockDim.x) {
        const float* s = bsrc + ((size_t)o * 512 + i) * 5;
        #pragma unroll
        for (int k = 0; k < 5; ++k)
            bdst[(size_t)o * 2560 + k * 512 + i] = f2bf(s[k]);
    }
}
__global__ void tsmooth_k(const float* __restrict__ src, u16* __restrict__ dst) {
    int o = blockIdx.x;                                      // smooth_w (OUT, in, K)
    for (int i = threadIdx.x; i < 512; i += blockDim.x) {
        const float* s = src + ((size_t)o * 512 + i) * 5;
        #pragma unroll
        for (int k = 0; k < 5; ++k)
            dst[(size_t)o * 2560 + k * 512 + i] = f2bf(s[k]);
    }
}
__global__ void cvt_bf_k(const float* __restrict__ in, u16* __restrict__ out, int n4) {
    int i = blockIdx.x * blockDim.x + threadIdx.x;
    if (i < n4) {
        float4 v = ((const float4*)in)[i];
        u32 lo = (u32)f2bf(v.x) | ((u32)f2bf(v.y) << 16);
        u32 hi = (u32)f2bf(v.z) | ((u32)f2bf(v.w) << 16);
        ((uint2*)out)[i] = make_uint2(lo, hi);
    }
}

enum { M_IDENT = 0, M_DECONV, M_CONV1, M_CONV2, M_EMBED, M_SMOOTH };
enum { E_BIAS = 1, E_LEAKY = 2, E_BN = 4, E_GELU = 8, E_RES = 16, E_OUTF = 32, E_OUTB = 64,
       E_QKVT = 128 };

// ---------------- 256x256 ring-3 GEMM (8 waves, BK=32, 96KB LDS) ----------------
// One barrier/tile; stage(t+2) issued into 3rd buffer BEFORE compute; counted vmcnt(8).
// LDS rows of 32 bf16 (64B); 16B-chunk c stored at c ^ ((row>>1)&3) via pre-swizzled source.
template<int EPI>
__global__ __launch_bounds__(512) void gemm256r_k(
    const u16* __restrict__ A, const u16* __restrict__ W,
    const float* __restrict__ bias,
    u16* __restrict__ outB, int gn, int N, int K)
{
    __shared__ u16 As[3][256 * 32];
    __shared__ u16 Bs[3][256 * 32];
    const int tid = threadIdx.x;
    const int lane = tid & 63, w = tid >> 6;
    const int l15 = lane & 15, hi4 = lane >> 4;
    const int nwg = gridDim.x;
    int wid = blockIdx.x;
    wid = (wid & 7) * (nwg >> 3) + (wid >> 3);
    const int bn = wid % gn, bm = wid / gn;
    const int wr = w >> 2, wc = w & 3;          // 2M x 4N wave grid
    const int lr = lane >> 2;
    const int lcs = ((lane & 3) ^ ((lane >> 3) & 3)) * 8;   // pre-swizzled source chunk
    f32x4 acc[8][4] = {};
    const int nt = K >> 5;

    const u16* abase[2];
    const u16* bbase[2];
    #pragma unroll
    for (int i = 0; i < 2; ++i) {
        abase[i] = A + (size_t)(bm * 256 + (w * 2 + i) * 16 + lr) * K + lcs;
        bbase[i] = W + (size_t)(bn * 256 + (w * 2 + i) * 16 + lr) * K + lcs;
    }

    auto stage = [&](int t, int buf) {
        #pragma unroll
        for (int i = 0; i < 2; ++i)
            gl_lds16(abase[i] + t * 32, &As[buf][(w * 2 + i) * 512]);
        #pragma unroll
        for (int i = 0; i < 2; ++i)
            gl_lds16(bbase[i] + t * 32, &Bs[buf][(w * 2 + i) * 512]);
    };

    auto compute = [&](int buf) {
        bf16x8 bq[4];
        #pragma unroll
        for (int ni = 0; ni < 4; ++ni) {
            const int C = wc * 64 + ni * 16 + l15;
            bq[ni] = *(const bf16x8*)&Bs[buf][C * 32 + (hi4 ^ ((C >> 1) & 3)) * 8];
        }
        bf16x8 af[8];
        #pragma unroll
        for (int mi = 0; mi < 8; ++mi) {
            const int R = wr * 128 + mi * 16 + l15;
            af[mi] = *(const bf16x8*)&As[buf][R * 32 + (hi4 ^ ((R >> 1) & 3)) * 8];
        }
        __builtin_amdgcn_s_setprio(1);
        #pragma unroll
        for (int mi = 0; mi < 8; ++mi)
            #pragma unroll
            for (int ni = 0; ni < 4; ++ni)   // swapped operands: lane m=l15, n=hi4*4+r
                acc[mi][ni] = __builtin_amdgcn_mfma_f32_16x16x32_bf16(bq[ni], af[mi], acc[mi][ni], 0, 0, 0);
        __builtin_amdgcn_s_setprio(0);
    };

    stage(0, 0);
    stage(1, 1);
    int cur = 0;
    for (int t = 0; t < nt; ++t) {
        __builtin_amdgcn_s_barrier();       // all waves done reading buf (t+2)%3 == (t-1)%3
        if (t + 2 < nt) {
            int nb = cur + 2; if (nb >= 3) nb -= 3;
            stage(t + 2, nb);               // overlaps the MFMA cluster below
            s_wait_vmcnt<8>();              // stage(t) landed; t+1,t+2 in flight
        } else if (t + 1 < nt) {
            s_wait_vmcnt<4>();
        } else {
            s_wait_vmcnt<0>();
        }
        compute(cur);
        ++cur; if (cur == 3) cur = 0;
    }

    // ---- epilogue ----
    #pragma unroll
    for (int mi = 0; mi < 8; ++mi) {
        const int row = bm * 256 + wr * 128 + mi * 16 + l15;
        #pragma unroll
        for (int ni = 0; ni < 4; ++ni) {
            const int col4 = bn * 256 + wc * 64 + ni * 16 + hi4 * 4;
            f32x4 v = acc[mi][ni];
            if constexpr (EPI & E_BIAS) {
                float4 bz = *(const float4*)&bias[col4];
                v[0] += bz.x; v[1] += bz.y; v[2] += bz.z; v[3] += bz.w;
            }
            if constexpr (EPI & E_GELU) {
                #pragma unroll
                for (int r = 0; r < 4; ++r) v[r] = gelu_f(v[r]);
            }
            if constexpr (EPI & E_OUTB) {
                u32 lo = (u32)f2bf(v[0]) | ((u32)f2bf(v[1]) << 16);
                u32 hi = (u32)f2bf(v[2]) | ((u32)f2bf(v[3]) << 16);
                *(uint2*)&outB[(size_t)row * N + col4] = make_uint2(lo, hi);
            }
        }
    }
}

// ---------------- universal GEMM: C[M,N] = gatherA[M,K](bf16) @ W[N,K](bf16) ----------------
template<int MODE, int EPI, int BM, int BN, int NT, int WM, int WN, int KSPLIT, int RING>
__global__ __launch_bounds__(NT) void gemm_k(
    const u16* __restrict__ A, const u16* __restrict__ W,
    const float* __restrict__ bias,
    const float* __restrict__ resid,
    float* __restrict__ outF, u16* __restrict__ outB, u16* __restrict__ outVT,
    const u16* __restrict__ zrow, int gn, int N, int K)
{
    constexpr int WAVES = NT / 64;
    static_assert(WM * WN == WAVES, "wave grid");
    constexpr int FM = BM / WM / 16, FN = BN / WN / 16;
    constexpr int APW = BM / (16 * WAVES), BPW = BN / (16 * WAVES);
    constexpr int LPW = APW + BPW;
    __shared__ u16 As[RING][BM * 32];
    __shared__ u16 Bs[RING][BN * 32];
    const int tid = threadIdx.x;
    const int lane = tid & 63, w = tid >> 6;
    const int l15 = lane & 15, hi4 = lane >> 4;
    const int nwg = gridDim.x;
    int wid = blockIdx.x;
    wid = (wid & 7) * (nwg >> 3) + (wid >> 3);
    const int mblocks = nwg / (gn * KSPLIT);
    const int bn = wid % gn;
    const int rem0 = wid / gn;
    const int bm = rem0 % mblocks;
    const int ks = rem0 / mblocks;
    const int Ksl = K / KSPLIT;
    const int kbase = ks * Ksl;
    const int wr = w / WN, wc = w % WN;
    const int rowb = wr * (BM / WM), colb = wc * (BN / WN);
    const int lr = lane >> 2;
    const int lcs = ((lane & 3) ^ ((lane >> 3) & 3)) * 8;   // pre-swizzled source chunk
    f32x4 acc[FM][FN] = {};
    const int nt = Ksl >> 5;

    const u16* bbase[BPW];
    #pragma unroll
    for (int p = 0; p < BPW; ++p) {
        const int j = w * BPW + p;
        bbase[p] = W + (size_t)(bn * BN + j * 16 + lr) * K + kbase + lcs;
    }
    const u16* abase[APW];
    #pragma unroll
    for (int p = 0; p < APW; ++p) {
        const int j = w * APW + p;
        if constexpr (MODE == M_IDENT)
            abase[p] = A + (size_t)(bm * BM + j * 16 + lr) * K + kbase + lcs;
        else
            abase[p] = nullptr;
    }

    auto stage = [&](int t, int buf) {
        const int k0 = kbase + t * 32;
        const int tap = k0 >> 9;
        const int koff = (k0 & 511) + lcs;
        u16* Ab = As[buf];
        u16* Bb = Bs[buf];
        #pragma unroll
        for (int p = 0; p < APW; ++p) {
            const int j = w * APW + p;
            const int r = j * 16 + lr;
            const int grow = bm * BM + r;
            const u16* src;
            if constexpr (MODE == M_IDENT) {
                src = abase[p] + t * 32;
            } else if constexpr (MODE == M_DECONV) {
                int b = grow >> 7, tt = grow & 127;
                int num = tt + 2 - tap;
                bool ok = (num >= 0) && ((num & 1) == 0) && ((num >> 1) < 64);
                src = ok ? (A + ((size_t)(b * 64 + (num >> 1))) * 512 + koff) : (zrow + koff);
            } else if constexpr (MODE == M_CONV1) {
                int b = grow >> 7, tt = grow & 127;
                int s = tt + tap - 2; s = s < 0 ? 0 : (s > 127 ? 127 : s);
                src = A + ((size_t)(b * 128 + s)) * 512 + koff;
            } else if constexpr (MODE == M_CONV2) {
                int b = grow >> 8, tt = grow & 255;
                int s = tt + tap - 2; s = s < 0 ? 0 : (s > 255 ? 255 : s);
                src = A + ((size_t)(b * 128 + (s >> 1))) * 512 + koff;
            } else if constexpr (MODE == M_EMBED) {
                int b = grow >> 9, tt = grow & 511;
                src = A + ((size_t)(b * 256 + (tt >> 1))) * 512 + koff;
            } else { // M_SMOOTH
                int b = grow >> 9, tt = grow & 511;
                int s = tt + tap - 2;
                bool ok = (s >= 0) && (s < 512);
                src = ok ? (A + ((size_t)(b * 512 + s)) * 512 + koff) : (zrow + koff);
            }
            gl_lds16(src, &Ab[j * 512]);
        }
        #pragma unroll
        for (int p = 0; p < BPW; ++p) {
            const int j = w * BPW + p;
            gl_lds16(bbase[p] + t * 32, &Bb[j * 512]);
        }
    };

    auto compute = [&](int buf) {
        const u16* Ab = As[buf];
        const u16* Bb = Bs[buf];
        bf16x8 af[FM], bfr[FN];
        #pragma unroll
        for (int mi = 0; mi < FM; ++mi) {
            const int R = rowb + mi * 16 + l15;
            af[mi] = *(const bf16x8*)&Ab[R * 32 + ((hi4 ^ ((R >> 1) & 3))) * 8];
        }
        #pragma unroll
        for (int ni = 0; ni < FN; ++ni) {
            const int R = colb + ni * 16 + l15;
            bfr[ni] = *(const bf16x8*)&Bb[R * 32 + ((hi4 ^ ((R >> 1) & 3))) * 8];
        }
        __builtin_amdgcn_s_setprio(1);
        #pragma unroll
        for (int mi = 0; mi < FM; ++mi)
            #pragma unroll
            for (int ni = 0; ni < FN; ++ni)   // swapped operands: lane m=l15, n=hi4*4+r
                acc[mi][ni] = __builtin_amdgcn_mfma_f32_16x16x32_bf16(bfr[ni], af[mi], acc[mi][ni], 0, 0, 0);
        __builtin_amdgcn_s_setprio(0);
    };

    #pragma unroll
    for (int i = 0; i < RING - 1; ++i)
        if (i < nt) stage(i, i);
    int cur = 0;
    for (int t = 0; t < nt; ++t) {
        if (t < nt - 1) s_wait_vmcnt<LPW>(); else s_wait_vmcnt<0>();
        __builtin_amdgcn_s_barrier();
        compute(cur);
        if (t + RING - 1 < nt) {
            int nb = cur + RING - 1; if (nb >= RING) nb -= RING;
            stage(t + RING - 1, nb);
        }
        ++cur; if (cur == RING) cur = 0;
    }

    if constexpr (KSPLIT > 1) {
        // bf16 partial: p[ks][row][col]
        const size_t Mrows = (size_t)mblocks * BM;
        #pragma unroll
        for (int mi = 0; mi < FM; ++mi) {
            const int row = bm * BM + rowb + mi * 16 + l15;
            #pragma unroll
            for (int ni = 0; ni < FN; ++ni) {
                const int col4 = bn * BN + colb + ni * 16 + hi4 * 4;
                f32x4 v = acc[mi][ni];
                u32 lo = (u32)f2bf(v[0]) | ((u32)f2bf(v[1]) << 16);
                u32 hi = (u32)f2bf(v[2]) | ((u32)f2bf(v[3]) << 16);
                *(uint2*)&outB[((size_t)ks * Mrows + row) * N + col4] = make_uint2(lo, hi);
            }
        }
        return;
    }

    // ---- epilogue (vectorized along N: 4 consecutive cols per lane) ----
    #pragma unroll
    for (int mi = 0; mi < FM; ++mi) {
        const int row = bm * BM + rowb + mi * 16 + l15;
        #pragma unroll
        for (int ni = 0; ni < FN; ++ni) {
            const int col4 = bn * BN + colb + ni * 16 + hi4 * 4;
            f32x4 v = acc[mi][ni];
            if constexpr (EPI & E_BIAS) {
                float4 bz = *(const float4*)&bias[col4];
                v[0] += bz.x; v[1] += bz.y; v[2] += bz.z; v[3] += bz.w;
            }
            if constexpr (EPI & E_LEAKY) {
                #pragma unroll
                for (int r = 0; r < 4; ++r) v[r] = v[r] >= 0.f ? v[r] : 0.2f * v[r];
            }
            if constexpr (EPI & E_GELU) {
                #pragma unroll
                for (int r = 0; r < 4; ++r) v[r] = gelu_f(v[r]);
            }
            if constexpr (EPI & E_RES) {
                float4 rz = *(const float4*)&resid[(size_t)row * N + col4];
                v[0] += rz.x; v[1] += rz.y; v[2] += rz.z; v[3] += rz.w;
            }
            bool vpart = false;
            if constexpr (EPI & E_QKVT) vpart = (col4 >= 1024);   // wave-uniform (128-aligned)
            if (vpart) {
                const int hh = (col4 - 1024) >> 6;
                const int dd = (col4 - 1024) & 63;
                const int bb = row >> 9, tt = row & 511;
                u16* vp = outVT + (((size_t)(bb * 8 + hh) * 64 + dd) * 512 + tt);
                #pragma unroll
                for (int r = 0; r < 4; ++r) vp[(size_t)r * 512] = f2bf(v[r]);
            } else {
                if constexpr (EPI & E_OUTF)
                    *(float4*)&outF[(size_t)row * N + col4] = make_float4(v[0], v[1], v[2], v[3]);
                if constexpr (EPI & E_OUTB) {
                    u32 lo = (u32)f2bf(v[0]) | ((u32)f2bf(v[1]) << 16);
                    u32 hi = (u32)f2bf(v[2]) | ((u32)f2bf(v[3]) << 16);
                    *(uint2*)&outB[(size_t)row * N + col4] = make_uint2(lo, hi);
                }
            }
        }
    }
}

// ---------------- split-K combine (bf16 partials): out = EPI(p0 + p1) ----------------
template<int EPI>
__global__ __launch_bounds__(256) void combine_k(
    const u16* __restrict__ p, size_t half,
    const float* __restrict__ bias,
    const float* __restrict__ bng, const float* __restrict__ bnbt,
    const float* __restrict__ bnm, const float* __restrict__ bnv,
    float* __restrict__ outF, u16* __restrict__ outB, int N, int n4)
{
    int i = blockIdx.x * 256 + threadIdx.x;
    if (i >= n4) return;
    uint2 pa = ((const uint2*)p)[i];
    uint2 pb = ((const uint2*)(p + half))[i];
    float v[4] = {bf2f((u16)pa.x) + bf2f((u16)pb.x),
                  bf2f((u16)(pa.x >> 16)) + bf2f((u16)(pb.x >> 16)),
                  bf2f((u16)pa.y) + bf2f((u16)pb.y),
                  bf2f((u16)(pa.y >> 16)) + bf2f((u16)(pb.y >> 16))};
    const int col4 = (i * 4) & (N - 1);
    if constexpr (EPI & E_BIAS) {
        float4 bz = *(const float4*)&bias[col4];
        v[0] += bz.x; v[1] += bz.y; v[2] += bz.z; v[3] += bz.w;
    }
    if constexpr (EPI & E_LEAKY) {
        #pragma unroll
        for (int r = 0; r < 4; ++r) v[r] = v[r] >= 0.f ? v[r] : 0.2f * v[r];
    }
    if constexpr (EPI & E_BN) {
        float4 gm = *(const float4*)&bng[col4];
        float4 bt = *(const float4*)&bnbt[col4];
        float4 mn = *(const float4*)&bnm[col4];
        float4 vr = *(const float4*)&bnv[col4];
        v[0] = (v[0] - mn.x) * (gm.x * rsqrtf(vr.x + 1e-5f)) + bt.x;
        v[1] = (v[1] - mn.y) * (gm.y * rsqrtf(vr.y + 1e-5f)) + bt.y;
        v[2] = (v[2] - mn.z) * (gm.z * rsqrtf(vr.z + 1e-5f)) + bt.z;
        v[3] = (v[3] - mn.w) * (gm.w * rsqrtf(vr.w + 1e-5f)) + bt.w;
    }
    if constexpr (EPI & E_OUTF)
        ((float4*)outF)[i] = make_float4(v[0], v[1], v[2], v[3]);
    if constexpr (EPI & E_OUTB) {
        u32 lo = (u32)f2bf(v[0]) | ((u32)f2bf(v[1]) << 16);
        u32 hi = (u32)f2bf(v[2]) | ((u32)f2bf(v[3]) << 16);
        ((uint2*)outB)[i] = make_uint2(lo, hi);
    }
}

// ---------------- combine(bf16 partials) + bf16 residual + LayerNorm (wave per 512-row) ----------------
__global__ __launch_bounds__(256) void lnc_k(
    const u16* __restrict__ p, size_t half,
    const float* __restrict__ bias, const u16* __restrict__ resid,
    const float* __restrict__ g, const float* __restrict__ bt,
    u16* __restrict__ outB)
{
    const int lane = threadIdx.x & 63, w = threadIdx.x >> 6;
    const size_t row = (size_t)blockIdx.x * 4 + w;
    const int c0 = lane * 8;
    const size_t o = row * 512 + c0;
    uint4 pa = *(const uint4*)&p[o];
    uint4 pb = *(const uint4*)&p[half + o];
    uint4 rz = *(const uint4*)&resid[o];
    float4 z0 = *(const float4*)&bias[c0];
    float4 z1 = *(const float4*)&bias[c0 + 4];
    u32 pa_[4] = {pa.x, pa.y, pa.z, pa.w};
    u32 pb_[4] = {pb.x, pb.y, pb.z, pb.w};
    u32 rz_[4] = {rz.x, rz.y, rz.z, rz.w};
    float zz[8] = {z0.x, z0.y, z0.z, z0.w, z1.x, z1.y, z1.z, z1.w};
    float v[8];
    #pragma unroll
    for (int i = 0; i < 4; ++i) {
        v[i * 2]     = bf2f((u16)pa_[i]) + bf2f((u16)pb_[i]) + bf2f((u16)rz_[i]) + zz[i * 2];
        v[i * 2 + 1] = bf2f((u16)(pa_[i] >> 16)) + bf2f((u16)(pb_[i] >> 16)) +
                       bf2f((u16)(rz_[i] >> 16)) + zz[i * 2 + 1];
    }
    float s = 0.f, q = 0.f;
    #pragma unroll
    for (int i = 0; i < 8; ++i) { s += v[i]; q += v[i] * v[i]; }
    #pragma unroll
    for (int d = 1; d < 64; d <<= 1) { s += __shfl_xor(s, d); q += __shfl_xor(q, d); }
    float mean = s * (1.f / 512.f);
    float var = q * (1.f / 512.f) - mean * mean;
    float rstd = rsqrtf(var + 1e-5f);
    float y[8];
    #pragma unroll
    for (int i = 0; i < 8; ++i) y[i] = (v[i] - mean) * rstd * g[c0 + i] + bt[c0 + i];
    u32 pk[4];
    #pragma unroll
    for (int i = 0; i < 4; ++i)
        pk[i] = (u32)f2bf(y[i * 2]) | ((u32)f2bf(y[i * 2 + 1]) << 16);
    *(uint4*)&outB[o] = make_uint4(pk[0], pk[1], pk[2], pk[3]);
}

// ---------------- flash attention ----------------
__global__ __launch_bounds__(256) void attn_k(const u16* __restrict__ qkv,
                                              const u16* __restrict__ vt,
                                              u16* __restrict__ outp)
{
    __shared__ u16 Ks[2][64 * 64];
    __shared__ u16 Vs[2][64 * 64];
    __shared__ u16 Ps[4][16 * 64];
    const int tid = threadIdx.x;
    const int lane = tid & 63, w = tid >> 6;
    const int l15 = lane & 15, hi4 = lane >> 4;
    const int qc = blockIdx.x, h = blockIdx.y, b = blockIdx.z;
    const int qrow = qc * 64 + w * 16 + l15;
    const size_t tq = ((size_t)b * 512 + qrow) * 1536 + h * 64;
    bf16x8 qf0 = *(const bf16x8*)&qkv[tq + hi4 * 8];
    bf16x8 qf1 = *(const bf16x8*)&qkv[tq + 32 + hi4 * 8];
    const float slope = exp2f(-(float)(h + 1));
    const f32x4 fz = {0.f, 0.f, 0.f, 0.f};
    float m_run = -3.0e38f, l_run = 0.f;
    f32x4 oacc[4] = {fz, fz, fz, fz};
    const int sr = lane >> 3;
    const int sc = ((lane & 7) ^ sr) * 8;
    const int pswz = (l15 & 7) << 3;

    auto stage = [&](int j, int buf) {
        #pragma unroll
        for (int p = 0; p < 2; ++p) {
            const int q8 = w * 2 + p;
            const int r = q8 * 8 + sr;
            gl_lds16(qkv + ((size_t)(b * 512 + j * 64 + r)) * 1536 + h * 64 + 512 + sc,
                     &Ks[buf][q8 * 512]);
            gl_lds16(vt + ((size_t)((b * 8 + h) * 64 + r)) * 512 + j * 64 + sc,
                     &Vs[buf][q8 * 512]);
        }
    };

    stage(0, 0);
    wait_vm0_barrier();
    int cur = 0;
    for (int j = 0; j < 8; ++j) {
        if (j < 7) stage(j + 1, cur ^ 1);
        const u16* Kb = Ks[cur];
        const u16* Vb = Vs[cur];
        float s[16];
        #pragma unroll
        for (int g = 0; g < 4; ++g) {
            f32x4 st = fz;
            const int row = g * 16 + l15;
            bf16x8 kf0 = *(const bf16x8*)&Kb[row * 64 + (hi4 ^ (row & 7)) * 8];
            st = __builtin_amdgcn_mfma_f32_16x16x32_bf16(kf0, qf0, st, 0, 0, 0);
            bf16x8 kf1 = *(const bf16x8*)&Kb[row * 64 + ((hi4 + 4) ^ (row & 7)) * 8];
            st = __builtin_amdgcn_mfma_f32_16x16x32_bf16(kf1, qf1, st, 0, 0, 0);
            #pragma unroll
            for (int r = 0; r < 4; ++r) {
                int kabs = j * 64 + g * 16 + hi4 * 4 + r;
                s[g * 4 + r] = st[r] * 0.125f - slope * fabsf((float)(qrow - kabs));
            }
        }
        float pm = s[0];
        #pragma unroll
        for (int i = 1; i < 16; ++i) pm = fmaxf(pm, s[i]);
        pm = fmaxf(pm, __shfl_xor(pm, 16));
        pm = fmaxf(pm, __shfl_xor(pm, 32));
        float m_new = fmaxf(m_run, pm);
        float alpha = __expf(m_run - m_new);
        float p[16], ps = 0.f;
        #pragma unroll
        for (int i = 0; i < 16; ++i) { p[i] = __expf(s[i] - m_new); ps += p[i]; }
        ps += __shfl_xor(ps, 16);
        ps += __shfl_xor(ps, 32);
        l_run = l_run * alpha + ps;
        m_run = m_new;
        #pragma unroll
        for (int n = 0; n < 4; ++n) oacc[n] *= alpha;
        #pragma unroll
        for (int g = 0; g < 4; ++g)
            #pragma unroll
            for (int rp = 0; rp < 2; ++rp) {
                u32 pk = (u32)f2bf(p[g * 4 + rp * 2]) | ((u32)f2bf(p[g * 4 + rp * 2 + 1]) << 16);
                const int o = g * 16 + hi4 * 4 + rp * 2;
                *(u32*)&Ps[w][l15 * 64 + (o ^ pswz)] = pk;
            }
        #pragma unroll
        for (int n = 0; n < 4; ++n) {
            const int d = n * 16 + l15;
            #pragma unroll
            for (int kk = 0; kk < 2; ++kk) {
                bf16x8 vf = *(const bf16x8*)&Vb[d * 64 + ((kk * 4 + hi4) ^ (d & 7)) * 8];
                bf16x8 pf = *(const bf16x8*)&Ps[w][l15 * 64 + ((kk * 32 + hi4 * 8) ^ pswz)];
                oacc[n] = __builtin_amdgcn_mfma_f32_16x16x32_bf16(vf, pf, oacc[n], 0, 0, 0);
            }
        }
        wait_vm0_barrier();
        cur ^= 1;
    }
    const float inv = 1.f / l_run;
    const size_t to = ((size_t)b * 512 + qrow) * 512 + h * 64;
    #pragma unroll
    for (int n = 0; n < 4; ++n) {
        u32 lo = (u32)f2bf(oacc[n][0] * inv) | ((u32)f2bf(oacc[n][1] * inv) << 16);
        u32 hi = (u32)f2bf(oacc[n][2] * inv) | ((u32)f2bf(oacc[n][3] * inv) << 16);
        *(uint2*)&outp[to + n * 16 + hi4 * 4] = make_uint2(lo, hi);
    }
}

extern "C" void kernel_launch(void* const* d_in, const int* in_sizes, int n_in,
                              void* d_out, int out_size, void* d_ws, size_t ws_size,
                              hipStream_t stream)
{
    (void)in_sizes; (void)n_in; (void)out_size; (void)ws_size;
    const float* inputs   = (const float*)d_in[0];
    const float* deconv_w = (const float*)d_in[1];
    const float* deconv_b = (const float*)d_in[2];
    const float* bn_gamma = (const float*)d_in[3];
    const float* bn_beta  = (const float*)d_in[4];
    const float* bn_mean  = (const float*)d_in[5];
    const float* bn_var   = (const float*)d_in[6];
    const float* conv_w   = (const float*)d_in[7];
    const float* conv_b   = (const float*)d_in[8];
    const float* emb_w    = (const float*)d_in[9];
    const float* emb_b    = (const float*)d_in[10];
    const float* qkv_w    = (const float*)d_in[11];
    const float* qkv_b    = (const float*)d_in[12];
    const float* outp_w   = (const float*)d_in[13];
    const float* outp_b   = (const float*)d_in[14];
    const float* ln1_g    = (const float*)d_in[15];
    const float* ln1_b    = (const float*)d_in[16];
    const float* ff1_w    = (const float*)d_in[17];
    const float* ff1_b    = (const float*)d_in[18];
    const float* ff2_w    = (const float*)d_in[19];
    const float* ff2_b    = (const float*)d_in[20];
    const float* ln2_g    = (const float*)d_in[21];
    const float* ln2_b    = (const float*)d_in[22];
    const float* smooth_w = (const float*)d_in[23];
    const float* smooth_b = (const float*)d_in[24];
    float* out = (float*)d_out;

    char* ws = (char*)d_ws;
    size_t off = 0;
    auto alloc = [&](size_t bytes) -> char* {
        char* p = ws + off;
        off += (bytes + 255) & ~(size_t)255;
        return p;
    };
    u16*   zrow    = (u16*)alloc(1024);
    u16*   Wd      = (u16*)alloc((size_t)512 * 2560 * 2);
    u16*   Wc      = (u16*)alloc((size_t)2 * 512 * 2560 * 2);
    u16*   Wsm     = (u16*)alloc((size_t)128 * 2560 * 2);
    u16*   emb_bw  = (u16*)alloc((size_t)512 * 512 * 2);
    u16*   qkv_bw  = (u16*)alloc((size_t)6 * 1536 * 512 * 2);
    u16*   outp_bw = (u16*)alloc((size_t)6 * 512 * 512 * 2);
    u16*   ff1_bw  = (u16*)alloc((size_t)6 * 2048 * 512 * 2);
    u16*   ff2_bw  = (u16*)alloc((size_t)6 * 512 * 2048 * 2);
    u16*   x_bf    = (u16*)alloc((size_t)8192 * 512 * 2);
    u16*   part_h  = (u16*)alloc((size_t)2 * 8192 * 512 * 2);   // bf16 split-K partials
    u16*   vtb     = (u16*)alloc((size_t)8192 * 512 * 2);
    char*  scratch = alloc((size_t)8192 * 2048 * 2);   // 32 MB aliased region
    u16*   in_bf   = (u16*)(scratch);                  // 1 MB
    u16*   e0      = (u16*)(scratch + (1 << 20));      // 2 MB
    u16*   e1      = (u16*)(scratch + (3 << 20));      // 2 MB
    u16*   e2      = (u16*)(scratch + (5 << 20));      // 4 MB
    u16*   qkv_bf  = (u16*)(scratch);                  // 24 MB
    u16*   attn_bf = (u16*)(scratch + (24 << 20));     // 8 MB
    u16*   h_bf    = (u16*)(scratch);                  // 32 MB

    hipMemsetAsync(zrow, 0, 1024, stream);
    // ---- weight prep (bf16) ----
    cvt_bf_k<<<dim3(512), dim3(256), 0, stream>>>(inputs, in_bf, 131072);
    tdeconv_k<<<dim3(512), dim3(256), 0, stream>>>(deconv_w, Wd);
    tconv_k<<<dim3(512, 2), dim3(256), 0, stream>>>(conv_w, Wc);
    tsmooth_k<<<dim3(128), dim3(256), 0, stream>>>(smooth_w, Wsm);
    cvt_bf_k<<<dim3(256), dim3(256), 0, stream>>>(emb_w, emb_bw, 65536);
    cvt_bf_k<<<dim3(4608), dim3(256), 0, stream>>>(qkv_w, qkv_bw, 1179648);
    cvt_bf_k<<<dim3(1536), dim3(256), 0, stream>>>(outp_w, outp_bw, 393216);
    cvt_bf_k<<<dim3(6144), dim3(256), 0, stream>>>(ff1_w, ff1_bw, 1572864);
    cvt_bf_k<<<dim3(6144), dim3(256), 0, stream>>>(ff2_w, ff2_bw, 1572864);

    const float* np = nullptr;
    u16* nu = nullptr;

    // ---- expander (all split-K=2 with combine; bf16 partials) ----
    gemm_k<M_DECONV, 0, 64, 64, 256, 2, 2, 2, 3><<<dim3(512), 256, 0, stream>>>(
        in_bf, Wd, np, np, nullptr, part_h, nu, zrow, 8, 512, 2560);
    combine_k<E_BIAS | E_LEAKY | E_BN | E_OUTB><<<dim3(1024), 256, 0, stream>>>(
        part_h, (size_t)2048 * 512, deconv_b, bn_gamma, bn_beta, bn_mean, bn_var,
        nullptr, e0, 512, 262144);
    gemm_k<M_CONV1, 0, 64, 64, 256, 2, 2, 2, 3><<<dim3(512), 256, 0, stream>>>(
        e0, Wc, np, np, nullptr, part_h, nu, zrow, 8, 512, 2560);
    combine_k<E_BIAS | E_LEAKY | E_BN | E_OUTB><<<dim3(1024), 256, 0, stream>>>(
        part_h, (size_t)2048 * 512, conv_b, bn_gamma + 512, bn_beta + 512, bn_mean + 512,
        bn_var + 512, nullptr, e1, 512, 262144);
    gemm_k<M_CONV2, 0, 64, 64, 256, 2, 2, 2, 3><<<dim3(1024), 256, 0, stream>>>(
        e1, Wc + (size_t)512 * 2560, np, np, nullptr, part_h, nu, zrow, 8, 512, 2560);
    combine_k<E_BIAS | E_LEAKY | E_BN | E_OUTB><<<dim3(2048), 256, 0, stream>>>(
        part_h, (size_t)4096 * 512, conv_b + 512, bn_gamma + 1024, bn_beta + 1024,
        bn_mean + 1024, bn_var + 1024, nullptr, e2, 512, 524288);
    gemm_k<M_EMBED, 0, 128, 64, 256, 4, 1, 2, 3><<<dim3(1024), 256, 0, stream>>>(
        e2, emb_bw, np, np, nullptr, part_h, nu, zrow, 8, 512, 512);
    combine_k<E_BIAS | E_OUTB><<<dim3(4096), 256, 0, stream>>>(
        part_h, (size_t)8192 * 512, emb_b, np, np, np, np, nullptr, x_bf, 512, 1048576);

    // ---- transformer (bf16 residual chain in x_bf) ----
    for (int l = 0; l < 6; ++l) {
        gemm_k<M_IDENT, E_BIAS | E_OUTB | E_QKVT, 128, 128, 256, 2, 2, 1, 3><<<dim3(768), 256, 0, stream>>>(
            x_bf, qkv_bw + (size_t)l * 1536 * 512, qkv_b + l * 1536,
            np, nullptr, qkv_bf, vtb, zrow, 12, 1536, 512);
        attn_k<<<dim3(8, 8, 16), 256, 0, stream>>>(qkv_bf, vtb, attn_bf);
        gemm_k<M_IDENT, 0, 128, 64, 256, 4, 1, 2, 3><<<dim3(1024), 256, 0, stream>>>(
            attn_bf, outp_bw + (size_t)l * 512 * 512, np,
            np, nullptr, part_h, nu, zrow, 8, 512, 512);
        lnc_k<<<dim3(2048), 256, 0, stream>>>(part_h, (size_t)8192 * 512,
            outp_b + l * 512, x_bf, ln1_g + l * 512, ln1_b + l * 512, x_bf);
        gemm256r_k<E_BIAS | E_GELU | E_OUTB><<<dim3(256), 512, 0, stream>>>(
            x_bf, ff1_bw + (size_t)l * 2048 * 512, ff1_b + l * 2048, h_bf, 8, 2048, 512);
        gemm_k<M_IDENT, 0, 128, 64, 256, 4, 1, 2, 3><<<dim3(1024), 256, 0, stream>>>(
            h_bf, ff2_bw + (size_t)l * 512 * 2048, np,
            np, nullptr, part_h, nu, zrow, 8, 512, 2048);
        lnc_k<<<dim3(2048), 256, 0, stream>>>(part_h, (size_t)8192 * 512,
            ff2_b + l * 512, x_bf, ln2_g + l * 512, ln2_b + l * 512, x_bf);
    }

    // ---- smooth conv -> output (split-K=2, bf16 partials) ----
    gemm_k<M_SMOOTH, 0, 64, 64, 256, 2, 2, 2, 3><<<dim3(512), 256, 0, stream>>>(
        x_bf, Wsm, np, np, nullptr, part_h, nu, zrow, 2, 128, 2560);
    combine_k<E_BIAS | E_OUTF><<<dim3(1024), 256, 0, stream>>>(
        part_h, (size_t)8192 * 128, smooth_b, np, np, np, np, out, nullptr, 128, 262144);
}

// Round 16
// 1003.713 us; speedup vs baseline: 1.0253x; 1.0253x over previous
//
#include <hip/hip_runtime.h>
#include <hip/hip_bf16.h>
#include <math.h>

typedef unsigned int u32;
typedef unsigned short u16;
typedef __bf16 bf16t;
typedef bf16t bf16x8 __attribute__((ext_vector_type(8)));
typedef float f32x4 __attribute__((ext_vector_type(4)));

__device__ __forceinline__ u16 f2bf(float f) {
    u32 u = __builtin_bit_cast(u32, f);
    u32 r = (u + 0x7fffu + ((u >> 16) & 1u)) >> 16;
    return (u16)r;
}
__device__ __forceinline__ float bf2f(u16 x) {
    u32 u = ((u32)x) << 16;
    return __builtin_bit_cast(float, u);
}

__device__ __forceinline__ float gelu_f(float x) {
    float z = fabsf(x) * 0.70710678118654752f;
    float t = 1.f / (1.f + 0.3275911f * z);
    float poly = t * (0.254829592f + t * (-0.284496736f + t * (1.421413741f +
                 t * (-1.453152027f + t * 1.061405429f))));
    float erfz = 1.f - poly * __expf(-z * z);
    erfz = copysignf(erfz, x);
    return 0.5f * x * (1.f + erfz);
}

__device__ __forceinline__ void gl_lds16(const u16* g, u16* l) {
    __builtin_amdgcn_global_load_lds(
        (const __attribute__((address_space(1))) void*)g,
        (__attribute__((address_space(3))) void*)l, 16, 0, 0);
}

__device__ __forceinline__ void wait_vm0_barrier() {
    asm volatile("s_waitcnt vmcnt(0)" ::: "memory");
    __builtin_amdgcn_s_barrier();
}

template<int N> __device__ __forceinline__ void s_wait_vmcnt() {
    if constexpr (N == 0) asm volatile("s_waitcnt vmcnt(0)" ::: "memory");
    else if constexpr (N == 2) asm volatile("s_waitcnt vmcnt(2)" ::: "memory");
    else if constexpr (N == 3) asm volatile("s_waitcnt vmcnt(3)" ::: "memory");
    else if constexpr (N == 4) asm volatile("s_waitcnt vmcnt(4)" ::: "memory");
    else if constexpr (N == 6) asm volatile("s_waitcnt vmcnt(6)" ::: "memory");
    else if constexpr (N == 8) asm volatile("s_waitcnt vmcnt(8)" ::: "memory");
    else static_assert(N == 0, "unsupported vmcnt");
}

// ---------------- weight layout transforms (-> bf16, (o, k*512+i)) ----------------
__global__ void tdeconv_k(const float* __restrict__ src, u16* __restrict__ dst) {
    int o = blockIdx.x;
    for (int i = threadIdx.x; i < 512; i += blockDim.x) {
        const float* s = src + ((size_t)i * 512 + o) * 5;   // deconv_w (in, out, K)
        #pragma unroll
        for (int k = 0; k < 5; ++k)
            dst[(size_t)o * 2560 + k * 512 + i] = f2bf(s[k]);
    }
}
__global__ void tconv_k(const float* __restrict__ src, u16* __restrict__ dst) {
    int o = blockIdx.x, st = blockIdx.y;
    const float* bsrc = src + (size_t)st * 512 * 512 * 5;   // conv_w (2, out, in, K)
    u16* bdst = dst + (size_t)st * 512 * 2560;
    for (int i = threadIdx.x; i < 512; i += blockDim.x) {
        const float* s = bsrc + ((size_t)o * 512 + i) * 5;
        #pragma unroll
        for (int k = 0; k < 5; ++k)
            bdst[(size_t)o * 2560 + k * 512 + i] = f2bf(s[k]);
    }
}
__global__ void tsmooth_k(const float* __restrict__ src, u16* __restrict__ dst) {
    int o = blockIdx.x;                                      // smooth_w (OUT, in, K)
    for (int i = threadIdx.x; i < 512; i += blockDim.x) {
        const float* s = src + ((size_t)o * 512 + i) * 5;
        #pragma unroll
        for (int k = 0; k < 5; ++k)
            dst[(size_t)o * 2560 + k * 512 + i] = f2bf(s[k]);
    }
}
__global__ void cvt_bf_k(const float* __restrict__ in, u16* __restrict__ out, int n4) {
    int i = blockIdx.x * blockDim.x + threadIdx.x;
    if (i < n4) {
        float4 v = ((const float4*)in)[i];
        u32 lo = (u32)f2bf(v.x) | ((u32)f2bf(v.y) << 16);
        u32 hi = (u32)f2bf(v.z) | ((u32)f2bf(v.w) << 16);
        ((uint2*)out)[i] = make_uint2(lo, hi);
    }
}

enum { M_IDENT = 0, M_DECONV, M_CONV1, M_CONV2, M_EMBED, M_SMOOTH };
enum { E_BIAS = 1, E_LEAKY = 2, E_BN = 4, E_GELU = 8, E_RES = 16, E_OUTF = 32, E_OUTB = 64,
       E_QKVT = 128 };

// ---------------- 256x256 double-buffered GEMM (8 waves, BK=64, 128KB LDS) ----------------
template<int EPI>
__global__ __launch_bounds__(512) void gemm256_k(
    const u16* __restrict__ A, const u16* __restrict__ W,
    const float* __restrict__ bias,
    u16* __restrict__ outB, int gn, int N, int K)
{
    __shared__ u16 As[2][256 * 64];
    __shared__ u16 Bs[2][256 * 64];
    const int tid = threadIdx.x;
    const int lane = tid & 63, w = tid >> 6;
    const int l15 = lane & 15, hi4 = lane >> 4;
    const int nwg = gridDim.x;
    int wid = blockIdx.x;
    wid = (wid & 7) * (nwg >> 3) + (wid >> 3);
    const int bn = wid % gn, bm = wid / gn;
    const int wr = w >> 2, wc = w & 3;          // 2M x 4N wave grid
    const int lr8 = lane >> 3;                  // row within 8-row group
    const int lcs8 = ((lane & 7) ^ lr8) * 8;    // pre-swizzled source chunk (elements)
    f32x4 acc[8][4] = {};
    const int nt = K >> 6;

    const u16* abase[4];
    const u16* bbase[4];
    #pragma unroll
    for (int i = 0; i < 4; ++i) {
        abase[i] = A + (size_t)(bm * 256 + w * 32 + i * 8 + lr8) * K + lcs8;
        bbase[i] = W + (size_t)(bn * 256 + w * 32 + i * 8 + lr8) * K + lcs8;
    }

    auto stage = [&](int t, int buf) {
        #pragma unroll
        for (int i = 0; i < 4; ++i)
            gl_lds16(abase[i] + t * 64, &As[buf][(w * 32 + i * 8) * 64]);
        #pragma unroll
        for (int i = 0; i < 4; ++i)
            gl_lds16(bbase[i] + t * 64, &Bs[buf][(w * 32 + i * 8) * 64]);
    };

    auto compute = [&](int buf) {
        #pragma unroll
        for (int ks = 0; ks < 2; ++ks) {
            bf16x8 bq[4];
            #pragma unroll
            for (int ni = 0; ni < 4; ++ni) {
                const int C = wc * 64 + ni * 16 + l15;
                bq[ni] = *(const bf16x8*)&Bs[buf][C * 64 + ((ks * 4 + hi4) ^ (C & 7)) * 8];
            }
            __builtin_amdgcn_s_setprio(1);
            #pragma unroll
            for (int mi = 0; mi < 8; ++mi) {
                const int R = wr * 128 + mi * 16 + l15;
                bf16x8 af = *(const bf16x8*)&As[buf][R * 64 + ((ks * 4 + hi4) ^ (R & 7)) * 8];
                #pragma unroll
                for (int ni = 0; ni < 4; ++ni)   // swapped operands: lane m=l15, n=hi4*4+r
                    acc[mi][ni] = __builtin_amdgcn_mfma_f32_16x16x32_bf16(bq[ni], af, acc[mi][ni], 0, 0, 0);
            }
            __builtin_amdgcn_s_setprio(0);
        }
    };

    stage(0, 0);
    stage(1, 1);
    for (int t = 0; t < nt; ++t) {
        if (t + 1 < nt) s_wait_vmcnt<8>(); else s_wait_vmcnt<0>();
        __builtin_amdgcn_s_barrier();
        compute(t & 1);
        __builtin_amdgcn_s_barrier();
        asm volatile("" ::: "memory");
        if (t + 2 < nt) stage(t + 2, t & 1);
    }

    // ---- epilogue ----
    #pragma unroll
    for (int mi = 0; mi < 8; ++mi) {
        const int row = bm * 256 + wr * 128 + mi * 16 + l15;
        #pragma unroll
        for (int ni = 0; ni < 4; ++ni) {
            const int col4 = bn * 256 + wc * 64 + ni * 16 + hi4 * 4;
            f32x4 v = acc[mi][ni];
            if constexpr (EPI & E_BIAS) {
                float4 bz = *(const float4*)&bias[col4];
                v[0] += bz.x; v[1] += bz.y; v[2] += bz.z; v[3] += bz.w;
            }
            if constexpr (EPI & E_GELU) {
                #pragma unroll
                for (int r = 0; r < 4; ++r) v[r] = gelu_f(v[r]);
            }
            if constexpr (EPI & E_OUTB) {
                u32 lo = (u32)f2bf(v[0]) | ((u32)f2bf(v[1]) << 16);
                u32 hi = (u32)f2bf(v[2]) | ((u32)f2bf(v[3]) << 16);
                *(uint2*)&outB[(size_t)row * N + col4] = make_uint2(lo, hi);
            }
        }
    }
}

// ---------------- universal GEMM: C[M,N] = gatherA[M,K](bf16) @ W[N,K](bf16) ----------------
template<int MODE, int EPI, int BM, int BN, int NT, int WM, int WN, int KSPLIT, int RING>
__global__ __launch_bounds__(NT) void gemm_k(
    const u16* __restrict__ A, const u16* __restrict__ W,
    const float* __restrict__ bias,
    const float* __restrict__ resid,
    float* __restrict__ outF, u16* __restrict__ outB, u16* __restrict__ outVT,
    const u16* __restrict__ zrow, int gn, int N, int K)
{
    constexpr int WAVES = NT / 64;
    static_assert(WM * WN == WAVES, "wave grid");
    constexpr int FM = BM / WM / 16, FN = BN / WN / 16;
    constexpr int APW = BM / (16 * WAVES), BPW = BN / (16 * WAVES);
    constexpr int LPW = APW + BPW;
    __shared__ u16 As[RING][BM * 32];
    __shared__ u16 Bs[RING][BN * 32];
    const int tid = threadIdx.x;
    const int lane = tid & 63, w = tid >> 6;
    const int l15 = lane & 15, hi4 = lane >> 4;
    const int nwg = gridDim.x;
    int wid = blockIdx.x;
    wid = (wid & 7) * (nwg >> 3) + (wid >> 3);
    const int mblocks = nwg / (gn * KSPLIT);
    const int bn = wid % gn;
    const int rem0 = wid / gn;
    const int bm = rem0 % mblocks;
    const int ks = rem0 / mblocks;
    const int Ksl = K / KSPLIT;
    const int kbase = ks * Ksl;
    const int wr = w / WN, wc = w % WN;
    const int rowb = wr * (BM / WM), colb = wc * (BN / WN);
    const int lr = lane >> 2;
    const int lcs = ((lane & 3) ^ ((lane >> 3) & 3)) * 8;   // pre-swizzled source chunk
    f32x4 acc[FM][FN] = {};
    const int nt = Ksl >> 5;

    const u16* bbase[BPW];
    #pragma unroll
    for (int p = 0; p < BPW; ++p) {
        const int j = w * BPW + p;
        bbase[p] = W + (size_t)(bn * BN + j * 16 + lr) * K + kbase + lcs;
    }
    const u16* abase[APW];
    #pragma unroll
    for (int p = 0; p < APW; ++p) {
        const int j = w * APW + p;
        if constexpr (MODE == M_IDENT)
            abase[p] = A + (size_t)(bm * BM + j * 16 + lr) * K + kbase + lcs;
        else
            abase[p] = nullptr;
    }

    auto stage = [&](int t, int buf) {
        const int k0 = kbase + t * 32;
        const int tap = k0 >> 9;
        const int koff = (k0 & 511) + lcs;
        u16* Ab = As[buf];
        u16* Bb = Bs[buf];
        #pragma unroll
        for (int p = 0; p < APW; ++p) {
            const int j = w * APW + p;
            const int r = j * 16 + lr;
            const int grow = bm * BM + r;
            const u16* src;
            if constexpr (MODE == M_IDENT) {
                src = abase[p] + t * 32;
            } else if constexpr (MODE == M_DECONV) {
                int b = grow >> 7, tt = grow & 127;
                int num = tt + 2 - tap;
                bool ok = (num >= 0) && ((num & 1) == 0) && ((num >> 1) < 64);
                src = ok ? (A + ((size_t)(b * 64 + (num >> 1))) * 512 + koff) : (zrow + koff);
            } else if constexpr (MODE == M_CONV1) {
                int b = grow >> 7, tt = grow & 127;
                int s = tt + tap - 2; s = s < 0 ? 0 : (s > 127 ? 127 : s);
                src = A + ((size_t)(b * 128 + s)) * 512 + koff;
            } else if constexpr (MODE == M_CONV2) {
                int b = grow >> 8, tt = grow & 255;
                int s = tt + tap - 2; s = s < 0 ? 0 : (s > 255 ? 255 : s);
                src = A + ((size_t)(b * 128 + (s >> 1))) * 512 + koff;
            } else if constexpr (MODE == M_EMBED) {
                int b = grow >> 9, tt = grow & 511;
                src = A + ((size_t)(b * 256 + (tt >> 1))) * 512 + koff;
            } else { // M_SMOOTH
                int b = grow >> 9, tt = grow & 511;
                int s = tt + tap - 2;
                bool ok = (s >= 0) && (s < 512);
                src = ok ? (A + ((size_t)(b * 512 + s)) * 512 + koff) : (zrow + koff);
            }
            gl_lds16(src, &Ab[j * 512]);
        }
        #pragma unroll
        for (int p = 0; p < BPW; ++p) {
            const int j = w * BPW + p;
            gl_lds16(bbase[p] + t * 32, &Bb[j * 512]);
        }
    };

    auto compute = [&](int buf) {
        const u16* Ab = As[buf];
        const u16* Bb = Bs[buf];
        bf16x8 af[FM], bfr[FN];
        #pragma unroll
        for (int mi = 0; mi < FM; ++mi) {
            const int R = rowb + mi * 16 + l15;
            af[mi] = *(const bf16x8*)&Ab[R * 32 + ((hi4 ^ ((R >> 1) & 3))) * 8];
        }
        #pragma unroll
        for (int ni = 0; ni < FN; ++ni) {
            const int R = colb + ni * 16 + l15;
            bfr[ni] = *(const bf16x8*)&Bb[R * 32 + ((hi4 ^ ((R >> 1) & 3))) * 8];
        }
        __builtin_amdgcn_s_setprio(1);
        #pragma unroll
        for (int mi = 0; mi < FM; ++mi)
            #pragma unroll
            for (int ni = 0; ni < FN; ++ni)   // swapped operands: lane m=l15, n=hi4*4+r
                acc[mi][ni] = __builtin_amdgcn_mfma_f32_16x16x32_bf16(bfr[ni], af[mi], acc[mi][ni], 0, 0, 0);
        __builtin_amdgcn_s_setprio(0);
    };

    #pragma unroll
    for (int i = 0; i < RING - 1; ++i)
        if (i < nt) stage(i, i);
    int cur = 0;
    for (int t = 0; t < nt; ++t) {
        if (t < nt - 1) s_wait_vmcnt<LPW>(); else s_wait_vmcnt<0>();
        __builtin_amdgcn_s_barrier();
        compute(cur);
        if (t + RING - 1 < nt) {
            int nb = cur + RING - 1; if (nb >= RING) nb -= RING;
            stage(t + RING - 1, nb);
        }
        ++cur; if (cur == RING) cur = 0;
    }

    if constexpr (KSPLIT > 1) {
        // bf16 partial: p[ks][row][col]
        const size_t Mrows = (size_t)mblocks * BM;
        #pragma unroll
        for (int mi = 0; mi < FM; ++mi) {
            const int row = bm * BM + rowb + mi * 16 + l15;
            #pragma unroll
            for (int ni = 0; ni < FN; ++ni) {
                const int col4 = bn * BN + colb + ni * 16 + hi4 * 4;
                f32x4 v = acc[mi][ni];
                u32 lo = (u32)f2bf(v[0]) | ((u32)f2bf(v[1]) << 16);
                u32 hi = (u32)f2bf(v[2]) | ((u32)f2bf(v[3]) << 16);
                *(uint2*)&outB[((size_t)ks * Mrows + row) * N + col4] = make_uint2(lo, hi);
            }
        }
        return;
    }

    // ---- epilogue (vectorized along N: 4 consecutive cols per lane) ----
    #pragma unroll
    for (int mi = 0; mi < FM; ++mi) {
        const int row = bm * BM + rowb + mi * 16 + l15;
        #pragma unroll
        for (int ni = 0; ni < FN; ++ni) {
            const int col4 = bn * BN + colb + ni * 16 + hi4 * 4;
            f32x4 v = acc[mi][ni];
            if constexpr (EPI & E_BIAS) {
                float4 bz = *(const float4*)&bias[col4];
                v[0] += bz.x; v[1] += bz.y; v[2] += bz.z; v[3] += bz.w;
            }
            if constexpr (EPI & E_LEAKY) {
                #pragma unroll
                for (int r = 0; r < 4; ++r) v[r] = v[r] >= 0.f ? v[r] : 0.2f * v[r];
            }
            if constexpr (EPI & E_GELU) {
                #pragma unroll
                for (int r = 0; r < 4; ++r) v[r] = gelu_f(v[r]);
            }
            if constexpr (EPI & E_RES) {
                float4 rz = *(const float4*)&resid[(size_t)row * N + col4];
                v[0] += rz.x; v[1] += rz.y; v[2] += rz.z; v[3] += rz.w;
            }
            bool vpart = false;
            if constexpr (EPI & E_QKVT) vpart = (col4 >= 1024);   // wave-uniform (128-aligned)
            if (vpart) {
                const int hh = (col4 - 1024) >> 6;
                const int dd = (col4 - 1024) & 63;
                const int bb = row >> 9, tt = row & 511;
                u16* vp = outVT + (((size_t)(bb * 8 + hh) * 64 + dd) * 512 + tt);
                #pragma unroll
                for (int r = 0; r < 4; ++r) vp[(size_t)r * 512] = f2bf(v[r]);
            } else {
                if constexpr (EPI & E_OUTF)
                    *(float4*)&outF[(size_t)row * N + col4] = make_float4(v[0], v[1], v[2], v[3]);
                if constexpr (EPI & E_OUTB) {
                    u32 lo = (u32)f2bf(v[0]) | ((u32)f2bf(v[1]) << 16);
                    u32 hi = (u32)f2bf(v[2]) | ((u32)f2bf(v[3]) << 16);
                    *(uint2*)&outB[(size_t)row * N + col4] = make_uint2(lo, hi);
                }
            }
        }
    }
}

// ---------------- split-K combine (bf16 partials): out = EPI(p0 + p1) ----------------
template<int EPI>
__global__ __launch_bounds__(256) void combine_k(
    const u16* __restrict__ p, size_t half,
    const float* __restrict__ bias,
    const float* __restrict__ bng, const float* __restrict__ bnbt,
    const float* __restrict__ bnm, const float* __restrict__ bnv,
    float* __restrict__ outF, u16* __restrict__ outB, int N, int n4)
{
    int i = blockIdx.x * 256 + threadIdx.x;
    if (i >= n4) return;
    uint2 pa = ((const uint2*)p)[i];
    uint2 pb = ((const uint2*)(p + half))[i];
    float v[4] = {bf2f((u16)pa.x) + bf2f((u16)pb.x),
                  bf2f((u16)(pa.x >> 16)) + bf2f((u16)(pb.x >> 16)),
                  bf2f((u16)pa.y) + bf2f((u16)pb.y),
                  bf2f((u16)(pa.y >> 16)) + bf2f((u16)(pb.y >> 16))};
    const int col4 = (i * 4) & (N - 1);
    if constexpr (EPI & E_BIAS) {
        float4 bz = *(const float4*)&bias[col4];
        v[0] += bz.x; v[1] += bz.y; v[2] += bz.z; v[3] += bz.w;
    }
    if constexpr (EPI & E_LEAKY) {
        #pragma unroll
        for (int r = 0; r < 4; ++r) v[r] = v[r] >= 0.f ? v[r] : 0.2f * v[r];
    }
    if constexpr (EPI & E_BN) {
        float4 gm = *(const float4*)&bng[col4];
        float4 bt = *(const float4*)&bnbt[col4];
        float4 mn = *(const float4*)&bnm[col4];
        float4 vr = *(const float4*)&bnv[col4];
        v[0] = (v[0] - mn.x) * (gm.x * rsqrtf(vr.x + 1e-5f)) + bt.x;
        v[1] = (v[1] - mn.y) * (gm.y * rsqrtf(vr.y + 1e-5f)) + bt.y;
        v[2] = (v[2] - mn.z) * (gm.z * rsqrtf(vr.z + 1e-5f)) + bt.z;
        v[3] = (v[3] - mn.w) * (gm.w * rsqrtf(vr.w + 1e-5f)) + bt.w;
    }
    if constexpr (EPI & E_OUTF)
        ((float4*)outF)[i] = make_float4(v[0], v[1], v[2], v[3]);
    if constexpr (EPI & E_OUTB) {
        u32 lo = (u32)f2bf(v[0]) | ((u32)f2bf(v[1]) << 16);
        u32 hi = (u32)f2bf(v[2]) | ((u32)f2bf(v[3]) << 16);
        ((uint2*)outB)[i] = make_uint2(lo, hi);
    }
}

// ---------------- combine(bf16 partials) + bf16 residual + LayerNorm (wave per 512-row) ----------------
__global__ __launch_bounds__(256) void lnc_k(
    const u16* __restrict__ p, size_t half,
    const float* __restrict__ bias, const u16* __restrict__ resid,
    const float* __restrict__ g, const float* __restrict__ bt,
    u16* __restrict__ outB)
{
    const int lane = threadIdx.x & 63, w = threadIdx.x >> 6;
    const size_t row = (size_t)blockIdx.x * 4 + w;
    const int c0 = lane * 8;
    const size_t o = row * 512 + c0;
    uint4 pa = *(const uint4*)&p[o];
    uint4 pb = *(const uint4*)&p[half + o];
    uint4 rz = *(const uint4*)&resid[o];
    float4 z0 = *(const float4*)&bias[c0];
    float4 z1 = *(const float4*)&bias[c0 + 4];
    u32 pa_[4] = {pa.x, pa.y, pa.z, pa.w};
    u32 pb_[4] = {pb.x, pb.y, pb.z, pb.w};
    u32 rz_[4] = {rz.x, rz.y, rz.z, rz.w};
    float zz[8] = {z0.x, z0.y, z0.z, z0.w, z1.x, z1.y, z1.z, z1.w};
    float v[8];
    #pragma unroll
    for (int i = 0; i < 4; ++i) {
        v[i * 2]     = bf2f((u16)pa_[i]) + bf2f((u16)pb_[i]) + bf2f((u16)rz_[i]) + zz[i * 2];
        v[i * 2 + 1] = bf2f((u16)(pa_[i] >> 16)) + bf2f((u16)(pb_[i] >> 16)) +
                       bf2f((u16)(rz_[i] >> 16)) + zz[i * 2 + 1];
    }
    float s = 0.f, q = 0.f;
    #pragma unroll
    for (int i = 0; i < 8; ++i) { s += v[i]; q += v[i] * v[i]; }
    #pragma unroll
    for (int d = 1; d < 64; d <<= 1) { s += __shfl_xor(s, d); q += __shfl_xor(q, d); }
    float mean = s * (1.f / 512.f);
    float var = q * (1.f / 512.f) - mean * mean;
    float rstd = rsqrtf(var + 1e-5f);
    float y[8];
    #pragma unroll
    for (int i = 0; i < 8; ++i) y[i] = (v[i] - mean) * rstd * g[c0 + i] + bt[c0 + i];
    u32 pk[4];
    #pragma unroll
    for (int i = 0; i < 4; ++i)
        pk[i] = (u32)f2bf(y[i * 2]) | ((u32)f2bf(y[i * 2 + 1]) << 16);
    *(uint4*)&outB[o] = make_uint4(pk[0], pk[1], pk[2], pk[3]);
}

// ---------------- flash attention ----------------
__global__ __launch_bounds__(256) void attn_k(const u16* __restrict__ qkv,
                                              const u16* __restrict__ vt,
                                              u16* __restrict__ outp)
{
    __shared__ u16 Ks[2][64 * 64];
    __shared__ u16 Vs[2][64 * 64];
    __shared__ u16 Ps[4][16 * 64];
    const int tid = threadIdx.x;
    const int lane = tid & 63, w = tid >> 6;
    const int l15 = lane & 15, hi4 = lane >> 4;
    const int qc = blockIdx.x, h = blockIdx.y, b = blockIdx.z;
    const int qrow = qc * 64 + w * 16 + l15;
    const size_t tq = ((size_t)b * 512 + qrow) * 1536 + h * 64;
    bf16x8 qf0 = *(const bf16x8*)&qkv[tq + hi4 * 8];
    bf16x8 qf1 = *(const bf16x8*)&qkv[tq + 32 + hi4 * 8];
    const float slope = exp2f(-(float)(h + 1));
    const f32x4 fz = {0.f, 0.f, 0.f, 0.f};
    float m_run = -3.0e38f, l_run = 0.f;
    f32x4 oacc[4] = {fz, fz, fz, fz};
    const int sr = lane >> 3;
    const int sc = ((lane & 7) ^ sr) * 8;
    const int pswz = (l15 & 7) << 3;

    auto stage = [&](int j, int buf) {
        #pragma unroll
        for (int p = 0; p < 2; ++p) {
            const int q8 = w * 2 + p;
            const int r = q8 * 8 + sr;
            gl_lds16(qkv + ((size_t)(b * 512 + j * 64 + r)) * 1536 + h * 64 + 512 + sc,
                     &Ks[buf][q8 * 512]);
            gl_lds16(vt + ((size_t)((b * 8 + h) * 64 + r)) * 512 + j * 64 + sc,
                     &Vs[buf][q8 * 512]);
        }
    };

    stage(0, 0);
    wait_vm0_barrier();
    int cur = 0;
    for (int j = 0; j < 8; ++j) {
        if (j < 7) stage(j + 1, cur ^ 1);
        const u16* Kb = Ks[cur];
        const u16* Vb = Vs[cur];
        float s[16];
        #pragma unroll
        for (int g = 0; g < 4; ++g) {
            f32x4 st = fz;
            const int row = g * 16 + l15;
            bf16x8 kf0 = *(const bf16x8*)&Kb[row * 64 + (hi4 ^ (row & 7)) * 8];
            st = __builtin_amdgcn_mfma_f32_16x16x32_bf16(kf0, qf0, st, 0, 0, 0);
            bf16x8 kf1 = *(const bf16x8*)&Kb[row * 64 + ((hi4 + 4) ^ (row & 7)) * 8];
            st = __builtin_amdgcn_mfma_f32_16x16x32_bf16(kf1, qf1, st, 0, 0, 0);
            #pragma unroll
            for (int r = 0; r < 4; ++r) {
                int kabs = j * 64 + g * 16 + hi4 * 4 + r;
                s[g * 4 + r] = st[r] * 0.125f - slope * fabsf((float)(qrow - kabs));
            }
        }
        float pm = s[0];
        #pragma unroll
        for (int i = 1; i < 16; ++i) pm = fmaxf(pm, s[i]);
        pm = fmaxf(pm, __shfl_xor(pm, 16));
        pm = fmaxf(pm, __shfl_xor(pm, 32));
        float m_new = fmaxf(m_run, pm);
        float alpha = __expf(m_run - m_new);
        float p[16], ps = 0.f;
        #pragma unroll
        for (int i = 0; i < 16; ++i) { p[i] = __expf(s[i] - m_new); ps += p[i]; }
        ps += __shfl_xor(ps, 16);
        ps += __shfl_xor(ps, 32);
        l_run = l_run * alpha + ps;
        m_run = m_new;
        #pragma unroll
        for (int n = 0; n < 4; ++n) oacc[n] *= alpha;
        #pragma unroll
        for (int g = 0; g < 4; ++g)
            #pragma unroll
            for (int rp = 0; rp < 2; ++rp) {
                u32 pk = (u32)f2bf(p[g * 4 + rp * 2]) | ((u32)f2bf(p[g * 4 + rp * 2 + 1]) << 16);
                const int o = g * 16 + hi4 * 4 + rp * 2;
                *(u32*)&Ps[w][l15 * 64 + (o ^ pswz)] = pk;
            }
        #pragma unroll
        for (int n = 0; n < 4; ++n) {
            const int d = n * 16 + l15;
            #pragma unroll
            for (int kk = 0; kk < 2; ++kk) {
                bf16x8 vf = *(const bf16x8*)&Vb[d * 64 + ((kk * 4 + hi4) ^ (d & 7)) * 8];
                bf16x8 pf = *(const bf16x8*)&Ps[w][l15 * 64 + ((kk * 32 + hi4 * 8) ^ pswz)];
                oacc[n] = __builtin_amdgcn_mfma_f32_16x16x32_bf16(vf, pf, oacc[n], 0, 0, 0);
            }
        }
        wait_vm0_barrier();
        cur ^= 1;
    }
    const float inv = 1.f / l_run;
    const size_t to = ((size_t)b * 512 + qrow) * 512 + h * 64;
    #pragma unroll
    for (int n = 0; n < 4; ++n) {
        u32 lo = (u32)f2bf(oacc[n][0] * inv) | ((u32)f2bf(oacc[n][1] * inv) << 16);
        u32 hi = (u32)f2bf(oacc[n][2] * inv) | ((u32)f2bf(oacc[n][3] * inv) << 16);
        *(uint2*)&outp[to + n * 16 + hi4 * 4] = make_uint2(lo, hi);
    }
}

extern "C" void kernel_launch(void* const* d_in, const int* in_sizes, int n_in,
                              void* d_out, int out_size, void* d_ws, size_t ws_size,
                              hipStream_t stream)
{
    (void)in_sizes; (void)n_in; (void)out_size; (void)ws_size;
    const float* inputs   = (const float*)d_in[0];
    const float* deconv_w = (const float*)d_in[1];
    const float* deconv_b = (const float*)d_in[2];
    const float* bn_gamma = (const float*)d_in[3];
    const float* bn_beta  = (const float*)d_in[4];
    const float* bn_mean  = (const float*)d_in[5];
    const float* bn_var   = (const float*)d_in[6];
    const float* conv_w   = (const float*)d_in[7];
    const float* conv_b   = (const float*)d_in[8];
    const float* emb_w    = (const float*)d_in[9];
    const float* emb_b    = (const float*)d_in[10];
    const float* qkv_w    = (const float*)d_in[11];
    const float* qkv_b    = (const float*)d_in[12];
    const float* outp_w   = (const float*)d_in[13];
    const float* outp_b   = (const float*)d_in[14];
    const float* ln1_g    = (const float*)d_in[15];
    const float* ln1_b    = (const float*)d_in[16];
    const float* ff1_w    = (const float*)d_in[17];
    const float* ff1_b    = (const float*)d_in[18];
    const float* ff2_w    = (const float*)d_in[19];
    const float* ff2_b    = (const float*)d_in[20];
    const float* ln2_g    = (const float*)d_in[21];
    const float* ln2_b    = (const float*)d_in[22];
    const float* smooth_w = (const float*)d_in[23];
    const float* smooth_b = (const float*)d_in[24];
    float* out = (float*)d_out;

    char* ws = (char*)d_ws;
    size_t off = 0;
    auto alloc = [&](size_t bytes) -> char* {
        char* p = ws + off;
        off += (bytes + 255) & ~(size_t)255;
        return p;
    };
    u16*   zrow    = (u16*)alloc(1024);
    u16*   Wd      = (u16*)alloc((size_t)512 * 2560 * 2);
    u16*   Wc      = (u16*)alloc((size_t)2 * 512 * 2560 * 2);
    u16*   Wsm     = (u16*)alloc((size_t)128 * 2560 * 2);
    u16*   emb_bw  = (u16*)alloc((size_t)512 * 512 * 2);
    u16*   qkv_bw  = (u16*)alloc((size_t)6 * 1536 * 512 * 2);
    u16*   outp_bw = (u16*)alloc((size_t)6 * 512 * 512 * 2);
    u16*   ff1_bw  = (u16*)alloc((size_t)6 * 2048 * 512 * 2);
    u16*   ff2_bw  = (u16*)alloc((size_t)6 * 512 * 2048 * 2);
    u16*   x_bf    = (u16*)alloc((size_t)8192 * 512 * 2);
    u16*   part_h  = (u16*)alloc((size_t)2 * 8192 * 512 * 2);   // bf16 split-K partials
    u16*   vtb     = (u16*)alloc((size_t)8192 * 512 * 2);
    char*  scratch = alloc((size_t)8192 * 2048 * 2);   // 32 MB aliased region
    u16*   in_bf   = (u16*)(scratch);                  // 1 MB
    u16*   e0      = (u16*)(scratch + (1 << 20));      // 2 MB
    u16*   e1      = (u16*)(scratch + (3 << 20));      // 2 MB
    u16*   e2      = (u16*)(scratch + (5 << 20));      // 4 MB
    u16*   qkv_bf  = (u16*)(scratch);                  // 24 MB
    u16*   attn_bf = (u16*)(scratch + (24 << 20));     // 8 MB
    u16*   h_bf    = (u16*)(scratch);                  // 32 MB

    hipMemsetAsync(zrow, 0, 1024, stream);
    // ---- weight prep (bf16) ----
    cvt_bf_k<<<dim3(512), dim3(256), 0, stream>>>(inputs, in_bf, 131072);
    tdeconv_k<<<dim3(512), dim3(256), 0, stream>>>(deconv_w, Wd);
    tconv_k<<<dim3(512, 2), dim3(256), 0, stream>>>(conv_w, Wc);
    tsmooth_k<<<dim3(128), dim3(256), 0, stream>>>(smooth_w, Wsm);
    cvt_bf_k<<<dim3(256), dim3(256), 0, stream>>>(emb_w, emb_bw, 65536);
    cvt_bf_k<<<dim3(4608), dim3(256), 0, stream>>>(qkv_w, qkv_bw, 1179648);
    cvt_bf_k<<<dim3(1536), dim3(256), 0, stream>>>(outp_w, outp_bw, 393216);
    cvt_bf_k<<<dim3(6144), dim3(256), 0, stream>>>(ff1_w, ff1_bw, 1572864);
    cvt_bf_k<<<dim3(6144), dim3(256), 0, stream>>>(ff2_w, ff2_bw, 1572864);

    const float* np = nullptr;
    u16* nu = nullptr;

    // ---- expander (all split-K=2 with combine; bf16 partials) ----
    gemm_k<M_DECONV, 0, 64, 64, 256, 2, 2, 2, 3><<<dim3(512), 256, 0, stream>>>(
        in_bf, Wd, np, np, nullptr, part_h, nu, zrow, 8, 512, 2560);
    combine_k<E_BIAS | E_LEAKY | E_BN | E_OUTB><<<dim3(1024), 256, 0, stream>>>(
        part_h, (size_t)2048 * 512, deconv_b, bn_gamma, bn_beta, bn_mean, bn_var,
        nullptr, e0, 512, 262144);
    gemm_k<M_CONV1, 0, 64, 64, 256, 2, 2, 2, 3><<<dim3(512), 256, 0, stream>>>(
        e0, Wc, np, np, nullptr, part_h, nu, zrow, 8, 512, 2560);
    combine_k<E_BIAS | E_LEAKY | E_BN | E_OUTB><<<dim3(1024), 256, 0, stream>>>(
        part_h, (size_t)2048 * 512, conv_b, bn_gamma + 512, bn_beta + 512, bn_mean + 512,
        bn_var + 512, nullptr, e1, 512, 262144);
    gemm_k<M_CONV2, 0, 64, 64, 256, 2, 2, 2, 3><<<dim3(1024), 256, 0, stream>>>(
        e1, Wc + (size_t)512 * 2560, np, np, nullptr, part_h, nu, zrow, 8, 512, 2560);
    combine_k<E_BIAS | E_LEAKY | E_BN | E_OUTB><<<dim3(2048), 256, 0, stream>>>(
        part_h, (size_t)4096 * 512, conv_b + 512, bn_gamma + 1024, bn_beta + 1024,
        bn_mean + 1024, bn_var + 1024, nullptr, e2, 512, 524288);
    gemm_k<M_EMBED, 0, 128, 64, 256, 4, 1, 2, 3><<<dim3(1024), 256, 0, stream>>>(
        e2, emb_bw, np, np, nullptr, part_h, nu, zrow, 8, 512, 512);
    combine_k<E_BIAS | E_OUTB><<<dim3(4096), 256, 0, stream>>>(
        part_h, (size_t)8192 * 512, emb_b, np, np, np, np, nullptr, x_bf, 512, 1048576);

    // ---- transformer (bf16 residual chain in x_bf) ----
    for (int l = 0; l < 6; ++l) {
        gemm_k<M_IDENT, E_BIAS | E_OUTB | E_QKVT, 128, 128, 256, 2, 2, 1, 3><<<dim3(768), 256, 0, stream>>>(
            x_bf, qkv_bw + (size_t)l * 1536 * 512, qkv_b + l * 1536,
            np, nullptr, qkv_bf, vtb, zrow, 12, 1536, 512);
        attn_k<<<dim3(8, 8, 16), 256, 0, stream>>>(qkv_bf, vtb, attn_bf);
        gemm_k<M_IDENT, 0, 128, 64, 256, 4, 1, 2, 3><<<dim3(1024), 256, 0, stream>>>(
            attn_bf, outp_bw + (size_t)l * 512 * 512, np,
            np, nullptr, part_h, nu, zrow, 8, 512, 512);
        lnc_k<<<dim3(2048), 256, 0, stream>>>(part_h, (size_t)8192 * 512,
            outp_b + l * 512, x_bf, ln1_g + l * 512, ln1_b + l * 512, x_bf);
        gemm256_k<E_BIAS | E_GELU | E_OUTB><<<dim3(256), 512, 0, stream>>>(
            x_bf, ff1_bw + (size_t)l * 2048 * 512, ff1_b + l * 2048, h_bf, 8, 2048, 512);
        gemm_k<M_IDENT, 0, 128, 64, 256, 4, 1, 2, 3><<<dim3(1024), 256, 0, stream>>>(
            h_bf, ff2_bw + (size_t)l * 512 * 2048, np,
            np, nullptr, part_h, nu, zrow, 8, 512, 2048);
        lnc_k<<<dim3(2048), 256, 0, stream>>>(part_h, (size_t)8192 * 512,
            ff2_b + l * 512, x_bf, ln2_g + l * 512, ln2_b + l * 512, x_bf);
    }

    // ---- smooth conv -> output (split-K=2, bf16 partials) ----
    gemm_k<M_SMOOTH, 0, 64, 64, 256, 2, 2, 2, 3><<<dim3(512), 256, 0, stream>>>(
        x_bf, Wsm, np, np, nullptr, part_h, nu, zrow, 2, 128, 2560);
    combine_k<E_BIAS | E_OUTF><<<dim3(1024), 256, 0, stream>>>(
        part_h, (size_t)8192 * 128, smooth_b, np, np, np, np, out, nullptr, 128, 262144);
}